// Round 2
// baseline (445.239 us; speedup 1.0000x reference)
//
#include <hip/hip_runtime.h>
#include <stdint.h>

// Problem constants (B,S,D,A fixed by the reference)
#define B_ 64
#define S_ 2048
#define D_ 512
#define A_ 256
#define TM 32          // tokens per block
#define NTILES 64      // S_/TM tiles per batch row
#define EPS 1e-7f

typedef short bf16x8 __attribute__((ext_vector_type(8)));
typedef float f32x4  __attribute__((ext_vector_type(4)));

// Workspace layout (bytes):
//  [0,      262144)  Wt   bf16 [A_][D_]   (W transposed, k-contiguous rows)
//  [262144, 393216)  num  f32  [B_][D_]   (atomic accumulator, zeroed by prep)
//  [393216, 393472)  Z    f32  [B_]
//  [393472, 393476)  mask-mode flag: 1 = byte mask, 0 = 4-byte mask
#define WS_WT   0
#define WS_NUM  262144
#define WS_Z    393216
#define WS_FLAG 393472

__device__ __forceinline__ uint32_t f32pair_to_bf16(float a, float b) {
  // round-to-nearest-even fp32 -> bf16, packed (a = low half / lower k index)
  uint32_t ua = __float_as_uint(a), ub = __float_as_uint(b);
  ua = (ua + 0x7fffu + ((ua >> 16) & 1u)) >> 16;
  ub = (ub + 0x7fffu + ((ub >> 16) & 1u)) & 0xffff0000u;
  return ua | ub;
}

__global__ __launch_bounds__(256) void prep_kernel(
    const float* __restrict__ W, const void* __restrict__ mask,
    uint16_t* __restrict__ Wt, float* __restrict__ num,
    float* __restrict__ Z, int* __restrict__ flag)
{
  int i = blockIdx.x * 256 + threadIdx.x;
  if (i < A_ * D_) {
    int a = i >> 9;            // D_=512
    int d = i & (D_ - 1);
    uint32_t u = __float_as_uint(W[d * A_ + a]);
    u = (u + 0x7fffu + ((u >> 16) & 1u)) >> 16;
    Wt[i] = (uint16_t)u;       // Wt[a][d]
  } else if (i < A_ * D_ + B_ * D_) {
    num[i - A_ * D_] = 0.0f;
  } else if (i < A_ * D_ + B_ * D_ + B_) {
    Z[i - A_ * D_ - B_ * D_] = 0.0f;
  }
  // Mask encoding detection: one wave scans the first 4KB (in-bounds for any encoding).
  // int8-packed words have all bytes in {0,1} with some byte1..3 nonzero;
  // int32 0/1 words have bytes1..3 == 0; float32 words are 0 or 0x3f800000.
  if (blockIdx.x == 0 && threadIdx.x < 64) {
    const uint32_t* mw = (const uint32_t*)mask;
    int hit = 0;
    for (int k = 0; k < 16; ++k) {
      uint32_t v = mw[threadIdx.x + 64 * k];
      uint32_t b0 = v & 0xff, b1 = (v >> 8) & 0xff, b2 = (v >> 16) & 0xff, b3 = v >> 24;
      if (b0 <= 1u && b1 <= 1u && b2 <= 1u && b3 <= 1u && (b1 | b2 | b3)) hit = 1;
    }
    hit = __any(hit);
    if (threadIdx.x == 0) *flag = hit ? 1 : 0;
  }
}

__global__ __launch_bounds__(256, 4) void att_main(
    const float* __restrict__ x, const void* __restrict__ mask,
    const float* __restrict__ bias, const float* __restrict__ uvec,
    const uint16_t* __restrict__ Wt, float* __restrict__ num,
    float* __restrict__ Z, const int* __restrict__ flag)
{
  // XOR-swizzled bf16 tile: logical (row, chunk c of 8 k's) stored at chunk c ^ (row&7).
  // Keeps A-fragment ds_read_b128 and numerator-phase reads at <=2-way aliasing (free).
  __shared__ uint16_t xs[TM * D_];   // 32768 B  -> 4 blocks/CU
  __shared__ float sp[4][TM];        // cross-wave score partials
  __shared__ float ev[TM];           // unnormalized weights e_s

  const int tid  = threadIdx.x;
  const int bx   = blockIdx.x;
  const int b    = bx >> 6;          // NTILES = 64
  const int tile = bx & 63;
  const int s0   = tile * TM;

  // ---- stage x tile: fp32 global -> bf16 LDS; loads batched for MLP ----
  const float* xb = x + ((size_t)b * S_ + (size_t)s0) * D_;
  #pragma unroll
  for (int half = 0; half < 2; ++half) {
    float4 v[4][2];
    #pragma unroll
    for (int c = 0; c < 4; ++c) {
      int p   = (half * 4 + c) * 256 + tid;   // 2048 chunks of 8 floats
      int row = p >> 6;
      int ch  = p & 63;
      const float* src = xb + row * D_ + ch * 8;
      v[c][0] = *(const float4*)(src);
      v[c][1] = *(const float4*)(src + 4);
    }
    #pragma unroll
    for (int c = 0; c < 4; ++c) {
      int p   = (half * 4 + c) * 256 + tid;
      int row = p >> 6;
      int ch  = p & 63;
      uint4 pk;
      pk.x = f32pair_to_bf16(v[c][0].x, v[c][0].y);
      pk.y = f32pair_to_bf16(v[c][0].z, v[c][0].w);
      pk.z = f32pair_to_bf16(v[c][1].x, v[c][1].y);
      pk.w = f32pair_to_bf16(v[c][1].z, v[c][1].w);
      int cc = ch ^ (row & 7);
      *(uint4*)(&xs[row * D_ + cc * 8]) = pk;
    }
  }
  __syncthreads();

  // ---- MFMA: wave w computes pre-act for all 32 tokens x n in [64w, 64w+64) ----
  const int l  = tid & 63;
  const int w  = tid >> 6;
  const int lr = l & 15;   // A: token-within-16; B: n-within-16; C: col (=n)
  const int lg = l >> 4;   // k-group; C: row-group

  f32x4 acc[2][4];
  #pragma unroll
  for (int mt = 0; mt < 2; ++mt)
    #pragma unroll
    for (int nt = 0; nt < 4; ++nt)
      acc[mt][nt] = (f32x4){0.f, 0.f, 0.f, 0.f};

  const uint16_t* WtBase = Wt + (size_t)(w * 64 + lr) * D_;

  #pragma unroll 4
  for (int ks = 0; ks < 16; ++ks) {
    bf16x8 af[2], bfr[4];
    #pragma unroll
    for (int mt = 0; mt < 2; ++mt) {
      int row = mt * 16 + lr;
      int cc  = (ks * 4 + lg) ^ (lr & 7);
      af[mt]  = *(const bf16x8*)(&xs[row * D_ + cc * 8]);
    }
    #pragma unroll
    for (int nt = 0; nt < 4; ++nt)
      bfr[nt] = *(const bf16x8*)(WtBase + nt * 16 * D_ + ks * 32 + lg * 8);
    #pragma unroll
    for (int mt = 0; mt < 2; ++mt)
      #pragma unroll
      for (int nt = 0; nt < 4; ++nt)
        acc[mt][nt] = __builtin_amdgcn_mfma_f32_16x16x32_bf16(af[mt], bfr[nt], acc[mt][nt], 0, 0, 0);
  }

  // ---- epilogue: uit = tanh(acc + bias); partial score = sum over wave's 64 n ----
  float bn[4], un[4];
  #pragma unroll
  for (int nt = 0; nt < 4; ++nt) {
    int n = w * 64 + nt * 16 + lr;
    bn[nt] = bias[n];
    un[nt] = uvec[n];
  }
  #pragma unroll
  for (int mt = 0; mt < 2; ++mt) {
    #pragma unroll
    for (int r = 0; r < 4; ++r) {
      float ssum = 0.0f;
      #pragma unroll
      for (int nt = 0; nt < 4; ++nt) {
        float v  = acc[mt][nt][r] + bn[nt];
        float av = fabsf(v);
        float e2 = __expf(-2.0f * av);
        float t  = 1.0f - 2.0f * e2 * __builtin_amdgcn_rcpf(1.0f + e2);  // tanh(|v|)
        ssum += copysignf(t, v) * un[nt];
      }
      // reduce across the 16 cols (lanes sharing lg)
      ssum += __shfl_xor(ssum, 1);
      ssum += __shfl_xor(ssum, 2);
      ssum += __shfl_xor(ssum, 4);
      ssum += __shfl_xor(ssum, 8);
      if (lr == 0) sp[w][mt * 16 + lg * 4 + r] = ssum;
    }
  }
  __syncthreads();

  // ---- e_s = exp(score)*mask; Z += sum(e) ----
  if (tid < TM) {
    float score = sp[0][tid] + sp[1][tid] + sp[2][tid] + sp[3][tid];
    int midx = b * S_ + s0 + tid;
    int mval;
    if (*flag) mval = ((const unsigned char*)mask)[midx] != 0;
    else       mval = ((const int*)mask)[midx] != 0;   // covers int32 and float32
    float e = mval ? __expf(score) : 0.0f;
    ev[tid] = e;
    float tot = e;
    #pragma unroll
    for (int o = 1; o < TM; o <<= 1) tot += __shfl_xor(tot, o);
    if (tid == 0) atomicAdd(&Z[b], tot);
  }
  __syncthreads();

  // ---- numerator partial: num[b][d] += sum_s e_s * x[s][d] (fp32 accum) ----
  {
    int d0 = tid * 2;
    int c0 = d0 >> 3;
    int j  = d0 & 7;
    float a0 = 0.0f, a1 = 0.0f;
    #pragma unroll 8
    for (int s = 0; s < TM; ++s) {
      int cc = c0 ^ (s & 7);
      uint32_t v = *(const uint32_t*)(&xs[s * D_ + cc * 8 + j]);
      float e = ev[s];
      a0 = fmaf(e, __uint_as_float(v << 16), a0);
      a1 = fmaf(e, __uint_as_float(v & 0xffff0000u), a1);
    }
    atomicAdd(&num[b * D_ + d0], a0);
    atomicAdd(&num[b * D_ + d0 + 1], a1);
  }
}

__global__ __launch_bounds__(256) void scale_kernel(
    const float* __restrict__ num, const float* __restrict__ Z,
    float* __restrict__ out)
{
  int idx = blockIdx.x * 256 + threadIdx.x;   // 32768 = B_*D_
  int b = idx >> 9;
  out[idx] = num[idx] / (Z[b] + EPS);
}

extern "C" void kernel_launch(void* const* d_in, const int* in_sizes, int n_in,
                              void* d_out, int out_size, void* d_ws, size_t ws_size,
                              hipStream_t stream)
{
  const float* x    = (const float*)d_in[0];
  const void*  mask = d_in[1];
  const float* W    = (const float*)d_in[2];
  const float* bias = (const float*)d_in[3];
  const float* u    = (const float*)d_in[4];
  float* out = (float*)d_out;

  char* ws = (char*)d_ws;
  uint16_t* Wt  = (uint16_t*)(ws + WS_WT);
  float* num    = (float*)(ws + WS_NUM);
  float* Z      = (float*)(ws + WS_Z);
  int*   flag   = (int*)(ws + WS_FLAG);

  int prep_threads = A_ * D_ + B_ * D_ + B_;
  prep_kernel<<<(prep_threads + 255) / 256, 256, 0, stream>>>(W, mask, Wt, num, Z, flag);
  att_main<<<B_ * NTILES, 256, 0, stream>>>(x, mask, bias, u, Wt, num, Z, flag);
  scale_kernel<<<(B_ * D_ + 255) / 256, 256, 0, stream>>>(num, Z, out);
}

// Round 3
// 378.967 us; speedup vs baseline: 1.1749x; 1.1749x over previous
//
#include <hip/hip_runtime.h>
#include <stdint.h>

// Problem constants (B,S,D,A fixed by the reference)
#define B_ 64
#define S_ 2048
#define D_ 512
#define A_ 256
#define TM 32          // tokens per tile
#define TPB 16         // tiles per block (block covers 512 tokens of one b)
#define NBLK 256       // B_*S_/(TM*TPB)
#define EPS 1e-7f

typedef short bf16x8 __attribute__((ext_vector_type(8)));
typedef float f32x4  __attribute__((ext_vector_type(4)));

// Workspace layout (bytes):
//  [0,      262144)  Wt    bf16 [A_][D_]   (W transposed, k-contiguous rows)
//  [262144, 786432)  part  f32  [NBLK][D_] (fully written every call)
//  [786432, 787456)  Zpart f32  [NBLK]
//  [787456, 787460)  mask-mode flag: 1 = byte mask, 0 = 4-byte mask
#define WS_WT   0
#define WS_PART 262144
#define WS_ZP   786432
#define WS_FLAG 787456

__device__ __forceinline__ uint32_t f32pair_to_bf16(float a, float b) {
  // round-to-nearest-even fp32 -> bf16, packed (a = low half / lower k index)
  uint32_t ua = __float_as_uint(a), ub = __float_as_uint(b);
  ua = (ua + 0x7fffu + ((ua >> 16) & 1u)) >> 16;
  ub = (ub + 0x7fffu + ((ub >> 16) & 1u)) & 0xffff0000u;
  return ua | ub;
}

__global__ __launch_bounds__(256) void prep_kernel(
    const float* __restrict__ W, const void* __restrict__ mask,
    uint16_t* __restrict__ Wt, int* __restrict__ flag)
{
  int i = blockIdx.x * 256 + threadIdx.x;
  if (i < A_ * D_) {
    int a = i >> 9;            // D_=512
    int d = i & (D_ - 1);
    uint32_t u = __float_as_uint(W[d * A_ + a]);
    u = (u + 0x7fffu + ((u >> 16) & 1u)) >> 16;
    Wt[i] = (uint16_t)u;       // Wt[a][d]
  }
  // Mask encoding detection: one wave scans the first 4KB (in-bounds for any encoding).
  // int8-packed words have all bytes in {0,1} with some byte1..3 nonzero;
  // int32 0/1 words have bytes1..3 == 0; float32 words are 0 or 0x3f800000.
  if (blockIdx.x == 0 && threadIdx.x < 64) {
    const uint32_t* mw = (const uint32_t*)mask;
    int hit = 0;
    for (int k = 0; k < 16; ++k) {
      uint32_t v = mw[threadIdx.x + 64 * k];
      uint32_t b0 = v & 0xff, b1 = (v >> 8) & 0xff, b2 = (v >> 16) & 0xff, b3 = v >> 24;
      if (b0 <= 1u && b1 <= 1u && b2 <= 1u && b3 <= 1u && (b1 | b2 | b3)) hit = 1;
    }
    hit = __any(hit);
    if (threadIdx.x == 0) *flag = hit ? 1 : 0;
  }
}

__global__ __launch_bounds__(512, 2) void att_main(
    const float* __restrict__ x, const void* __restrict__ mask,
    const float* __restrict__ bias, const float* __restrict__ uvec,
    const uint16_t* __restrict__ Wt, float* __restrict__ part,
    float* __restrict__ Zpart, const int* __restrict__ flag)
{
  // Double-buffered XOR-swizzled bf16 x-tile: chunk c of row stored at c^(row&7)
  // within its 8-chunk group -> all LDS phases <=2-way bank aliasing (free).
  __shared__ uint16_t xs[2][TM * D_];   // 2 x 32 KB
  __shared__ float sp[8][TM];           // cross-wave score partials
  __shared__ float ev[TM];              // unnormalized weights e_s

  const int tid = threadIdx.x;
  const int l  = tid & 63, w  = tid >> 6;   // 8 waves
  const int lr = l & 15,   lg = l >> 4;
  const int bx = blockIdx.x;
  const int b  = bx >> 2;                   // 4 blocks per batch row
  const int s0 = (bx & 3) * (TM * TPB);
  const float* xb = x + ((size_t)b * S_ + s0) * D_;
  const int mflag = *flag;

  // ---- Wt B-fragments resident in VGPRs for the whole block (128 VGPRs) ----
  // wave w owns a in [32w, 32w+32): nt in {0,1} 16-wide MFMA tiles
  bf16x8 bfr[32];
  {
    const uint16_t* wtb = Wt + (size_t)(w * 32 + lr) * D_;
    #pragma unroll
    for (int ks = 0; ks < 16; ++ks)
      #pragma unroll
      for (int nt = 0; nt < 2; ++nt)
        bfr[ks * 2 + nt] = *(const bf16x8*)(wtb + nt * 16 * D_ + ks * 32 + lg * 8);
  }
  float bn[2], un[2];
  #pragma unroll
  for (int nt = 0; nt < 2; ++nt) {
    int n = w * 32 + nt * 16 + lr;
    bn[nt] = bias[n];
    un[nt] = uvec[n];
  }

  float num_acc = 0.0f;   // this thread's d-column (d = tid), summed over all 512 tokens
  float zacc    = 0.0f;   // block partial of Z (tid 0 only)

  // preload tile 0 (8 x float4 per thread = 64KB/block)
  float4 v[4][2];
  #pragma unroll
  for (int c = 0; c < 4; ++c) {
    int q = c * 512 + tid;                 // 32B granules
    const float* src = xb + (q >> 6) * D_ + (q & 63) * 8;
    v[c][0] = *(const float4*)src;
    v[c][1] = *(const float4*)(src + 4);
  }

  for (int t = 0; t < TPB; ++t) {
    uint16_t* buf = xs[t & 1];

    // ---- pack fp32 -> bf16, store to LDS ----
    #pragma unroll
    for (int c = 0; c < 4; ++c) {
      int q = c * 512 + tid;
      int row = q >> 6, cb = q & 63;
      uint4 pk;
      pk.x = f32pair_to_bf16(v[c][0].x, v[c][0].y);
      pk.y = f32pair_to_bf16(v[c][0].z, v[c][0].w);
      pk.z = f32pair_to_bf16(v[c][1].x, v[c][1].y);
      pk.w = f32pair_to_bf16(v[c][1].z, v[c][1].w);
      *(uint4*)(&buf[row * D_ + (cb ^ (row & 7)) * 8]) = pk;
    }
    __syncthreads();

    // ---- issue next tile's global loads; they drain under this tile's compute ----
    if (t + 1 < TPB) {
      const float* xt = xb + (size_t)(t + 1) * TM * D_;
      #pragma unroll
      for (int c = 0; c < 4; ++c) {
        int q = c * 512 + tid;
        const float* src = xt + (q >> 6) * D_ + (q & 63) * 8;
        v[c][0] = *(const float4*)src;
        v[c][1] = *(const float4*)(src + 4);
      }
    }

    // ---- MFMA: A from LDS, B from registers ----
    f32x4 acc[2][2];
    #pragma unroll
    for (int mt = 0; mt < 2; ++mt)
      #pragma unroll
      for (int nt = 0; nt < 2; ++nt)
        acc[mt][nt] = (f32x4){0.f, 0.f, 0.f, 0.f};

    #pragma unroll
    for (int ks = 0; ks < 16; ++ks) {
      bf16x8 af[2];
      #pragma unroll
      for (int mt = 0; mt < 2; ++mt)
        af[mt] = *(const bf16x8*)(&buf[(mt * 16 + lr) * D_ + (((ks * 4 + lg) ^ (lr & 7)) * 8)]);
      #pragma unroll
      for (int mt = 0; mt < 2; ++mt)
        #pragma unroll
        for (int nt = 0; nt < 2; ++nt)
          acc[mt][nt] = __builtin_amdgcn_mfma_f32_16x16x32_bf16(af[mt], bfr[ks * 2 + nt], acc[mt][nt], 0, 0, 0);
    }

    // ---- epilogue: tanh(acc+bias)*u, reduce over this wave's 32 a ----
    #pragma unroll
    for (int mt = 0; mt < 2; ++mt) {
      #pragma unroll
      for (int r = 0; r < 4; ++r) {
        float ssum = 0.0f;
        #pragma unroll
        for (int nt = 0; nt < 2; ++nt) {
          float vv = acc[mt][nt][r] + bn[nt];
          float av = fabsf(vv);
          float e2 = __expf(-2.0f * av);
          float th = 1.0f - 2.0f * e2 * __builtin_amdgcn_rcpf(1.0f + e2);
          ssum += copysignf(th, vv) * un[nt];
        }
        ssum += __shfl_xor(ssum, 1);
        ssum += __shfl_xor(ssum, 2);
        ssum += __shfl_xor(ssum, 4);
        ssum += __shfl_xor(ssum, 8);
        if (lr == 0) sp[w][mt * 16 + lg * 4 + r] = ssum;
      }
    }
    __syncthreads();

    // ---- e_s = exp(score)*mask; Z partial in a register ----
    if (tid < TM) {
      float score = 0.0f;
      #pragma unroll
      for (int ww = 0; ww < 8; ++ww) score += sp[ww][tid];
      int midx = b * S_ + s0 + t * TM + tid;
      int mv = mflag ? (((const unsigned char*)mask)[midx] != 0)
                     : (((const int*)mask)[midx] != 0);
      float e = mv ? __expf(score) : 0.0f;
      ev[tid] = e;
      float tot = e;
      #pragma unroll
      for (int o = 1; o < TM; o <<= 1) tot += __shfl_xor(tot, o);
      if (tid == 0) zacc += tot;
    }
    __syncthreads();

    // ---- numerator: num_acc += sum_s e_s * x[s][d], d = tid ----
    // lanes d and d^1 read the same 4B word (broadcast); 32 words cover 32 banks.
    {
      int c = tid >> 3, wo = (tid & 7) >> 1;
      #pragma unroll 8
      for (int s = 0; s < TM; ++s) {
        uint32_t vv = *(const uint32_t*)(&buf[s * D_ + (c ^ (s & 7)) * 8 + wo * 2]);
        float xv = (tid & 1) ? __uint_as_float(vv & 0xffff0000u)
                             : __uint_as_float(vv << 16);
        num_acc = fmaf(ev[s], xv, num_acc);
      }
    }
  }

  part[(size_t)bx * D_ + tid] = num_acc;
  if (tid == 0) Zpart[bx] = zacc;
}

__global__ __launch_bounds__(256) void scale_kernel(
    const float* __restrict__ part, const float* __restrict__ Zpart,
    float* __restrict__ out)
{
  int idx = blockIdx.x * 256 + threadIdx.x;   // 32768 = B_*D_
  int b = idx >> 9;
  int d = idx & (D_ - 1);
  float s = 0.0f, z = 0.0f;
  #pragma unroll
  for (int g = 0; g < 4; ++g) {
    s += part[(size_t)(b * 4 + g) * D_ + d];
    z += Zpart[b * 4 + g];
  }
  out[idx] = s / (z + EPS);
}

extern "C" void kernel_launch(void* const* d_in, const int* in_sizes, int n_in,
                              void* d_out, int out_size, void* d_ws, size_t ws_size,
                              hipStream_t stream)
{
  const float* x    = (const float*)d_in[0];
  const void*  mask = d_in[1];
  const float* W    = (const float*)d_in[2];
  const float* bias = (const float*)d_in[3];
  const float* u    = (const float*)d_in[4];
  float* out = (float*)d_out;

  char* ws = (char*)d_ws;
  uint16_t* Wt  = (uint16_t*)(ws + WS_WT);
  float* part   = (float*)(ws + WS_PART);
  float* Zpart  = (float*)(ws + WS_ZP);
  int*   flag   = (int*)(ws + WS_FLAG);

  prep_kernel<<<(A_ * D_ + 255) / 256, 256, 0, stream>>>(W, mask, Wt, flag);
  att_main<<<NBLK, 512, 0, stream>>>(x, mask, bias, u, Wt, part, Zpart, flag);
  scale_kernel<<<(B_ * D_ + 255) / 256, 256, 0, stream>>>(part, Zpart, out);
}

// Round 4
// 371.956 us; speedup vs baseline: 1.1970x; 1.0189x over previous
//
#include <hip/hip_runtime.h>
#include <stdint.h>

// Problem constants (B,S,D,A fixed by the reference)
#define B_ 64
#define S_ 2048
#define D_ 512
#define A_ 256
#define TM 32          // tokens per tile
#define TPB 16         // tiles per block (block covers 512 tokens of one b)
#define NBLK 256       // B_*S_/(TM*TPB)
#define EPS 1e-7f

typedef short bf16x8 __attribute__((ext_vector_type(8)));
typedef float f32x4  __attribute__((ext_vector_type(4)));

// Workspace layout (bytes):
//  [0,      262144)  Wt    bf16 [A_][D_]   (W transposed, k-contiguous rows)
//  [262144, 786432)  part  f32  [NBLK][D_] (fully written every call)
//  [786432, 787456)  Zpart f32  [NBLK]
//  [787456, 787460)  mask-mode flag: 1 = byte mask, 0 = 4-byte mask
#define WS_WT   0
#define WS_PART 262144
#define WS_ZP   786432
#define WS_FLAG 787456

__device__ __forceinline__ uint32_t f32pair_to_bf16(float a, float b) {
  // round-to-nearest-even fp32 -> bf16, packed (a = low half / lower k index)
  uint32_t ua = __float_as_uint(a), ub = __float_as_uint(b);
  ua = (ua + 0x7fffu + ((ua >> 16) & 1u)) >> 16;
  ub = (ub + 0x7fffu + ((ub >> 16) & 1u)) & 0xffff0000u;
  return ua | ub;
}

// async global->LDS, 16B per lane; lds base must be wave-uniform (HW adds lane*16)
__device__ __forceinline__ void gload_lds16(const float* g, float* l) {
  __builtin_amdgcn_global_load_lds(
      (const __attribute__((address_space(1))) uint32_t*)g,
      (__attribute__((address_space(3))) uint32_t*)l, 16, 0, 0);
}

// sum over the 16-lane DPP row via 4 VALU-latency DPP adds (all lanes get the sum)
__device__ __forceinline__ float row16_sum(float x) {
  int v = __float_as_int(x);
  x += __int_as_float(__builtin_amdgcn_update_dpp(v, v, 0xB1, 0xF, 0xF, false));  // quad xor1
  v = __float_as_int(x);
  x += __int_as_float(__builtin_amdgcn_update_dpp(v, v, 0x4E, 0xF, 0xF, false));  // quad xor2
  v = __float_as_int(x);
  x += __int_as_float(__builtin_amdgcn_update_dpp(v, v, 0x141, 0xF, 0xF, false)); // half mirror
  v = __float_as_int(x);
  x += __int_as_float(__builtin_amdgcn_update_dpp(v, v, 0x128, 0xF, 0xF, false)); // row ror:8
  return x;
}

__global__ __launch_bounds__(256) void prep_kernel(
    const float* __restrict__ W, const void* __restrict__ mask,
    uint16_t* __restrict__ Wt, int* __restrict__ flag)
{
  int i = blockIdx.x * 256 + threadIdx.x;
  if (i < A_ * D_) {
    int a = i >> 9;            // D_=512
    int d = i & (D_ - 1);
    uint32_t u = __float_as_uint(W[d * A_ + a]);
    u = (u + 0x7fffu + ((u >> 16) & 1u)) >> 16;
    Wt[i] = (uint16_t)u;       // Wt[a][d]
  }
  // Mask encoding detection (one wave, first 4KB; see R0 notes)
  if (blockIdx.x == 0 && threadIdx.x < 64) {
    const uint32_t* mw = (const uint32_t*)mask;
    int hit = 0;
    for (int k = 0; k < 16; ++k) {
      uint32_t v = mw[threadIdx.x + 64 * k];
      uint32_t b0 = v & 0xff, b1 = (v >> 8) & 0xff, b2 = (v >> 16) & 0xff, b3 = v >> 24;
      if (b0 <= 1u && b1 <= 1u && b2 <= 1u && b3 <= 1u && (b1 | b2 | b3)) hit = 1;
    }
    hit = __any(hit);
    if (threadIdx.x == 0) *flag = hit ? 1 : 0;
  }
}

__global__ __launch_bounds__(512, 2) void att_main(
    const float* __restrict__ x, const void* __restrict__ mask,
    const float* __restrict__ bias, const float* __restrict__ uvec,
    const uint16_t* __restrict__ Wt, float* __restrict__ part,
    float* __restrict__ Zpart, const int* __restrict__ flag)
{
  // fp32 staging buffer (written by global_load_lds). Physical b128-chunk p of a row
  // holds logical chunk: p<64 -> 2p (even), p>=64 -> 2(p-64)+1 (odd). This makes the
  // pack-phase reads bank-conflict-free.
  __shared__ float xf[TM * D_];          // 64 KB
  // double-buffered XOR-swizzled bf16 tile: chunk c of row stored at c^(row&7)
  __shared__ uint16_t xs[2][TM * D_];    // 2 x 32 KB
  __shared__ float sp[8][TM];            // per-wave score partials
  __shared__ float me[TM * TPB];         // mask as 0/1 float for this block's 512 tokens

  const int tid = threadIdx.x;
  const int l  = tid & 63, w  = tid >> 6;   // 8 waves
  const int lr = l & 15,   lg = l >> 4;
  const int bx = blockIdx.x;
  const int b  = bx >> 2;                   // 4 blocks per batch row
  const int s0 = (bx & 3) * (TM * TPB);
  const float* xb = x + ((size_t)b * S_ + s0) * D_;
  const int mflag = *flag;

  // ---- mask -> LDS (once per block) ----
  {
    int midx = b * S_ + s0 + tid;
    int mv = mflag ? (((const unsigned char*)mask)[midx] != 0)
                   : (((const int*)mask)[midx] != 0);
    me[tid] = mv ? 1.0f : 0.0f;
  }

  // ---- Wt B-fragments resident in VGPRs for the whole block (128 VGPRs) ----
  bf16x8 bfr[32];
  {
    const uint16_t* wtb = Wt + (size_t)(w * 32 + lr) * D_;
    #pragma unroll
    for (int ks = 0; ks < 16; ++ks)
      #pragma unroll
      for (int nt = 0; nt < 2; ++nt)
        bfr[ks * 2 + nt] = *(const bf16x8*)(wtb + nt * 16 * D_ + ks * 32 + lg * 8);
  }
  float bn[2], un[2];
  #pragma unroll
  for (int nt = 0; nt < 2; ++nt) {
    int n = w * 32 + nt * 16 + lr;
    bn[nt] = bias[n];
    un[nt] = uvec[n];
  }

  float num_acc = 0.0f;   // this thread's d-column (d = tid) over all 512 tokens
  float zacc    = 0.0f;   // Z partial (tid 0)

  // ---- async-load tile 0 (each wave: 8 windows of 1KB) ----
  #pragma unroll
  for (int i = 0; i < 8; ++i) {
    int id = w * 8 + i, row = id >> 1, h = id & 1;
    gload_lds16(xb + row * D_ + (2 * l + h) * 4, &xf[row * D_ + h * 256]);
  }
  __syncthreads();   // drains vmcnt -> xf(tile0) ready; me visible

  // ---- pack tile 0 into xs[0] ----
  #pragma unroll
  for (int c = 0; c < 4; ++c) {
    int row = c * 8 + w;
    float4 lo = *(const float4*)&xf[row * D_ + l * 4];
    float4 hi = *(const float4*)&xf[row * D_ + 256 + l * 4];
    uint4 pk;
    pk.x = f32pair_to_bf16(lo.x, lo.y);
    pk.y = f32pair_to_bf16(lo.z, lo.w);
    pk.z = f32pair_to_bf16(hi.x, hi.y);
    pk.w = f32pair_to_bf16(hi.z, hi.w);
    *(uint4*)(&xs[0][row * D_ + ((l ^ (row & 7)) * 8)]) = pk;
  }
  __syncthreads();   // xs[0] visible; xf free

  // ---- async-load tile 1 ----
  {
    const float* xt = xb + (size_t)TM * D_;
    #pragma unroll
    for (int i = 0; i < 8; ++i) {
      int id = w * 8 + i, row = id >> 1, h = id & 1;
      gload_lds16(xt + row * D_ + (2 * l + h) * 4, &xf[row * D_ + h * 256]);
    }
  }

  #pragma unroll 2
  for (int t = 0; t < TPB; ++t) {
    const uint16_t* buf = xs[t & 1];

    // ---- MFMA: A from bf16 LDS, B from registers ----
    f32x4 acc[2][2];
    #pragma unroll
    for (int mt = 0; mt < 2; ++mt)
      #pragma unroll
      for (int nt = 0; nt < 2; ++nt)
        acc[mt][nt] = (f32x4){0.f, 0.f, 0.f, 0.f};

    #pragma unroll
    for (int ks = 0; ks < 16; ++ks) {
      bf16x8 af[2];
      #pragma unroll
      for (int mt = 0; mt < 2; ++mt)
        af[mt] = *(const bf16x8*)(&buf[(mt * 16 + lr) * D_ + (((ks * 4 + lg) ^ (lr & 7)) * 8)]);
      #pragma unroll
      for (int mt = 0; mt < 2; ++mt)
        #pragma unroll
        for (int nt = 0; nt < 2; ++nt)
          acc[mt][nt] = __builtin_amdgcn_mfma_f32_16x16x32_bf16(af[mt], bfr[ks * 2 + nt], acc[mt][nt], 0, 0, 0);
    }

    // ---- epilogue: tanh(acc+bias)*u, DPP-reduce over this wave's 32 a ----
    #pragma unroll
    for (int mt = 0; mt < 2; ++mt) {
      #pragma unroll
      for (int r = 0; r < 4; ++r) {
        float ssum = 0.0f;
        #pragma unroll
        for (int nt = 0; nt < 2; ++nt) {
          float vv = acc[mt][nt][r] + bn[nt];
          float av = fabsf(vv);
          float e2 = __expf(-2.0f * av);
          float th = 1.0f - 2.0f * e2 * __builtin_amdgcn_rcpf(1.0f + e2);
          ssum += copysignf(th, vv) * un[nt];
        }
        ssum = row16_sum(ssum);
        if (lr == 0) sp[w][mt * 16 + lg * 4 + r] = ssum;
      }
    }
    __syncthreads();   // bar1: sp visible; vmcnt(0) drain -> xf(t+1) ready

    // ---- pack tile t+1 (fp32 LDS -> bf16 LDS, other parity buffer) ----
    if (t + 1 < TPB) {
      uint16_t* nb = xs[(t + 1) & 1];
      #pragma unroll
      for (int c = 0; c < 4; ++c) {
        int row = c * 8 + w;
        float4 lo = *(const float4*)&xf[row * D_ + l * 4];
        float4 hi = *(const float4*)&xf[row * D_ + 256 + l * 4];
        uint4 pk;
        pk.x = f32pair_to_bf16(lo.x, lo.y);
        pk.y = f32pair_to_bf16(lo.z, lo.w);
        pk.z = f32pair_to_bf16(hi.x, hi.y);
        pk.w = f32pair_to_bf16(hi.z, hi.w);
        *(uint4*)(&nb[row * D_ + ((l ^ (row & 7)) * 8)]) = pk;
      }
    }

    // ---- e_s per wave (lanes 0..31), Z partial in wave 0 ----
    float eval = 0.0f;
    if (l < 32) {
      float sc = 0.0f;
      #pragma unroll
      for (int ww = 0; ww < 8; ++ww) sc += sp[ww][l];
      eval = me[t * TM + l] * __expf(sc);
    }
    if (w == 0 && l < 32) {
      float tot = eval;
      tot += __shfl_xor(tot, 1);
      tot += __shfl_xor(tot, 2);
      tot += __shfl_xor(tot, 4);
      tot += __shfl_xor(tot, 8);
      tot += __shfl_xor(tot, 16);
      if (l == 0) zacc += tot;
    }

    // ---- numerator: num_acc += sum_s e_s * x[s][d], d = tid (bf16 tile) ----
    {
      int cw = tid >> 3, wo = (tid & 7) >> 1;
      #pragma unroll
      for (int s = 0; s < TM; ++s) {
        float e = __int_as_float(__builtin_amdgcn_readlane(__float_as_int(eval), s));
        uint32_t vv = *(const uint32_t*)(&buf[s * D_ + (cw ^ (s & 7)) * 8 + wo * 2]);
        float xv = (tid & 1) ? __uint_as_float(vv & 0xffff0000u)
                             : __uint_as_float(vv << 16);
        num_acc = fmaf(e, xv, num_acc);
      }
    }
    __syncthreads();   // bar2: xs[(t+1)&1] visible; xf reads done

    // ---- async-load tile t+2 into xf ----
    if (t + 2 < TPB) {
      const float* xt = xb + (size_t)(t + 2) * TM * D_;
      #pragma unroll
      for (int i = 0; i < 8; ++i) {
        int id = w * 8 + i, row = id >> 1, h = id & 1;
        gload_lds16(xt + row * D_ + (2 * l + h) * 4, &xf[row * D_ + h * 256]);
      }
    }
  }

  part[(size_t)bx * D_ + tid] = num_acc;
  if (tid == 0) Zpart[bx] = zacc;
}

__global__ __launch_bounds__(256) void scale_kernel(
    const float* __restrict__ part, const float* __restrict__ Zpart,
    float* __restrict__ out)
{
  int idx = blockIdx.x * 256 + threadIdx.x;   // 32768 = B_*D_
  int b = idx >> 9;
  int d = idx & (D_ - 1);
  float s = 0.0f, z = 0.0f;
  #pragma unroll
  for (int g = 0; g < 4; ++g) {
    s += part[(size_t)(b * 4 + g) * D_ + d];
    z += Zpart[b * 4 + g];
  }
  out[idx] = s / (z + EPS);
}

extern "C" void kernel_launch(void* const* d_in, const int* in_sizes, int n_in,
                              void* d_out, int out_size, void* d_ws, size_t ws_size,
                              hipStream_t stream)
{
  const float* x    = (const float*)d_in[0];
  const void*  mask = d_in[1];
  const float* W    = (const float*)d_in[2];
  const float* bias = (const float*)d_in[3];
  const float* u    = (const float*)d_in[4];
  float* out = (float*)d_out;

  char* ws = (char*)d_ws;
  uint16_t* Wt  = (uint16_t*)(ws + WS_WT);
  float* part   = (float*)(ws + WS_PART);
  float* Zpart  = (float*)(ws + WS_ZP);
  int*   flag   = (int*)(ws + WS_FLAG);

  prep_kernel<<<(A_ * D_ + 255) / 256, 256, 0, stream>>>(W, mask, Wt, flag);
  att_main<<<NBLK, 512, 0, stream>>>(x, mask, bias, u, Wt, part, Zpart, flag);
  scale_kernel<<<(B_ * D_ + 255) / 256, 256, 0, stream>>>(part, Zpart, out);
}